// Round 10
// baseline (380.626 us; speedup 1.0000x reference)
//
#include <hip/hip_runtime.h>
#include <hip/hip_bf16.h>
#include <math.h>

#define HID 128
#define HEADS 4
#define CH 32
#define OUTD 6
#define SLOPE 0.2f
#define LNEPS 1e-5f

static inline int cdiv(int a, int b) { return (a + b - 1) / b; }

__device__ __forceinline__ unsigned short f2bf(float f) {
    unsigned int u = __builtin_bit_cast(unsigned int, f);
    u += 0x7FFFu + ((u >> 16) & 1u);   // round-to-nearest-even
    return (unsigned short)(u >> 16);
}
__device__ __forceinline__ float bflo(unsigned int u) {
    return __builtin_bit_cast(float, u << 16);
}
__device__ __forceinline__ float bfhi(unsigned int u) {
    return __builtin_bit_cast(float, u & 0xFFFF0000u);
}

// ---------------- CSR build ----------------
// deg starts at 1: the self-loop of node i owns rank 0 (scattered in fused scan3).
// count/scatter passes then cover only the E random edges.

__global__ void k_init_deg(int* __restrict__ deg, int n) {
    int i = blockIdx.x * 256 + threadIdx.x;
    if (i < n) deg[i] = 1;
}

__global__ void k_count_rank(const int* __restrict__ ei, int E,
                             int* __restrict__ deg, int* __restrict__ epos) {
    int e = blockIdx.x * 256 + threadIdx.x;
    if (e >= E) return;
    int dst = ei[E + e];
    epos[e] = atomicAdd(&deg[dst], 1);
}

__global__ __launch_bounds__(1024) void k_scan1(const int* __restrict__ deg, int n,
                                                int* __restrict__ ex, int* __restrict__ bsum) {
    __shared__ int sw[16];
    int i = blockIdx.x * 1024 + threadIdx.x;
    int v = (i < n) ? deg[i] : 0;
    int lane = threadIdx.x & 63, w = threadIdx.x >> 6;
    int x = v;
    #pragma unroll
    for (int d = 1; d < 64; d <<= 1) {
        int t = __shfl_up(x, d);
        if (lane >= d) x += t;
    }
    if (lane == 63) sw[w] = x;
    __syncthreads();
    if (w == 0) {
        int t = (lane < 16) ? sw[lane] : 0;
        #pragma unroll
        for (int d = 1; d < 16; d <<= 1) {
            int u = __shfl_up(t, d);
            if (lane >= d) t += u;
        }
        if (lane < 16) sw[lane] = t;
    }
    __syncthreads();
    int woff = (w > 0) ? sw[w - 1] : 0;
    int incl = x + woff;
    if (i < n) ex[i] = incl - v;
    if (threadIdx.x == 1023) bsum[blockIdx.x] = incl;
}

__global__ void k_scan2(int* __restrict__ bsum, int nb) {
    int lane = threadIdx.x;
    int v = (lane < nb) ? bsum[lane] : 0;
    int x = v;
    #pragma unroll
    for (int d = 1; d < 64; d <<= 1) {
        int t = __shfl_up(x, d);
        if (lane >= d) x += t;
    }
    if (lane < nb) bsum[lane] = x - v;
}

// fused: finalize offsets AND scatter the self-loop (rank 0 slot of each node)
__global__ __launch_bounds__(1024) void k_scan3(int* __restrict__ ex, const int* __restrict__ bsum,
                                                int n, int* __restrict__ csr_src) {
    int i = blockIdx.x * 1024 + threadIdx.x;
    if (i < n) {
        int off = ex[i] + bsum[blockIdx.x];
        ex[i] = off;
        csr_src[off] = i;
    }
}

__global__ void k_scatter(const int* __restrict__ ei, const int* __restrict__ epos,
                          const int* __restrict__ offsets, int E,
                          int* __restrict__ csr_src) {
    int e = blockIdx.x * 256 + threadIdx.x;
    if (e >= E) return;
    int src = ei[e], dst = ei[E + e];
    csr_src[offsets[dst] + epos[e]] = src;
}

// ---------------- fused dual linear: outL = X@Wl (bf16), outR = X@Wr (bf16) ----------------
// 128 threads/block, 32 nodes/block, 16 nodes/wave: keeps high FMA-per-W-load
// (latency hiding) while grid = N/32 = 1563 blocks (~6/CU) for occupancy.
template <int K>
__global__ __launch_bounds__(128) void dual_linear(const float* __restrict__ X,
                                                   const float* __restrict__ Wl,
                                                   const float* __restrict__ Wr,
                                                   unsigned short* __restrict__ outL,
                                                   unsigned short* __restrict__ outR, int n) {
    __shared__ float sX[32][K + 4];
    int tid = threadIdx.x;
    int tx = tid & 63;
    int ty = tid >> 6;
    int node0 = blockIdx.x * 32;

    constexpr int C4 = K / 4;
    constexpr int NQ = (32 * C4) / 128;   // K=32: 2, K=128: 8
    #pragma unroll
    for (int q = 0; q < NQ; ++q) {
        int g = q * 128 + tid;
        int row = g / C4, c4 = g % C4;
        int gn = node0 + row;
        float4 v = make_float4(0.f, 0.f, 0.f, 0.f);
        if (gn < n) v = *(const float4*)&X[(size_t)gn * K + c4 * 4];
        *(float4*)&sX[row][c4 * 4] = v;
    }
    __syncthreads();

    const float* Wbase = (tx < 32) ? (Wl + tx * 4) : (Wr + (tx - 32) * 4);

    float4 acc[16];
    #pragma unroll
    for (int i = 0; i < 16; ++i) acc[i] = make_float4(0.f, 0.f, 0.f, 0.f);

    #pragma unroll 2
    for (int k4 = 0; k4 < K / 4; ++k4) {
        const float* wp = Wbase + (size_t)k4 * 4 * HID;
        float4 w0 = *(const float4*)(wp);
        float4 w1 = *(const float4*)(wp + HID);
        float4 w2 = *(const float4*)(wp + 2 * HID);
        float4 w3 = *(const float4*)(wp + 3 * HID);
        #pragma unroll
        for (int i = 0; i < 16; ++i) {
            float4 xq = *(const float4*)&sX[ty * 16 + i][k4 * 4];
            acc[i].x = fmaf(xq.x, w0.x, acc[i].x);
            acc[i].y = fmaf(xq.x, w0.y, acc[i].y);
            acc[i].z = fmaf(xq.x, w0.z, acc[i].z);
            acc[i].w = fmaf(xq.x, w0.w, acc[i].w);
            acc[i].x = fmaf(xq.y, w1.x, acc[i].x);
            acc[i].y = fmaf(xq.y, w1.y, acc[i].y);
            acc[i].z = fmaf(xq.y, w1.z, acc[i].z);
            acc[i].w = fmaf(xq.y, w1.w, acc[i].w);
            acc[i].x = fmaf(xq.z, w2.x, acc[i].x);
            acc[i].y = fmaf(xq.z, w2.y, acc[i].y);
            acc[i].z = fmaf(xq.z, w2.z, acc[i].z);
            acc[i].w = fmaf(xq.z, w2.w, acc[i].w);
            acc[i].x = fmaf(xq.w, w3.x, acc[i].x);
            acc[i].y = fmaf(xq.w, w3.y, acc[i].y);
            acc[i].z = fmaf(xq.w, w3.z, acc[i].z);
            acc[i].w = fmaf(xq.w, w3.w, acc[i].w);
        }
    }

    int c = tx * 4;
    unsigned short* basep = (c < HID) ? outL : outR;
    int cc = (c < HID) ? c : c - HID;
    #pragma unroll
    for (int i = 0; i < 16; ++i) {
        int gn = node0 + ty * 16 + i;
        if (gn < n) {
            ushort4 o;
            o.x = f2bf(acc[i].x); o.y = f2bf(acc[i].y);
            o.z = f2bf(acc[i].z); o.w = f2bf(acc[i].w);
            *(ushort4*)&basep[(size_t)gn * HID + cc] = o;
        }
    }
}

// ---------------- GATv2 aggregation with fused LN(+residual)+ELU epilogue ----------------
// one wave per dst node; lane lc=lane&15 owns 8 channels (head = lc>>2),
// eg=lane>>4 = edge slot -> 4-edge groups with 4 gathers in flight.

struct GatAcc {
    float den;
    float nb[8];
};

template <bool CHECKED>
__device__ __forceinline__ void gat_edge(uint4 r, bool valid,
                                         const float4& xrA, const float4& xrB,
                                         const float4& atA, const float4& atB,
                                         GatAcc& g) {
    float e0 = bflo(r.x), e1 = bfhi(r.x);
    float e2 = bflo(r.y), e3 = bfhi(r.y);
    float e4 = bflo(r.z), e5 = bfhi(r.z);
    float e6 = bflo(r.w), e7 = bfhi(r.w);
    float v0 = e0 + xrA.x; v0 = fmaxf(v0, SLOPE * v0);
    float v1 = e1 + xrA.y; v1 = fmaxf(v1, SLOPE * v1);
    float v2 = e2 + xrA.z; v2 = fmaxf(v2, SLOPE * v2);
    float v3 = e3 + xrA.w; v3 = fmaxf(v3, SLOPE * v3);
    float v4 = e4 + xrB.x; v4 = fmaxf(v4, SLOPE * v4);
    float v5 = e5 + xrB.y; v5 = fmaxf(v5, SLOPE * v5);
    float v6 = e6 + xrB.z; v6 = fmaxf(v6, SLOPE * v6);
    float v7 = e7 + xrB.w; v7 = fmaxf(v7, SLOPE * v7);
    float t = v0 * atA.x;
    t = fmaf(v1, atA.y, t);
    t = fmaf(v2, atA.z, t);
    t = fmaf(v3, atA.w, t);
    t = fmaf(v4, atB.x, t);
    t = fmaf(v5, atB.y, t);
    t = fmaf(v6, atB.z, t);
    t = fmaf(v7, atB.w, t);
    t += __shfl_xor(t, 1);
    t += __shfl_xor(t, 2);
    float a = __expf(t);
    if (CHECKED) a = valid ? a : 0.f;
    g.den += a;
    g.nb[0] = fmaf(a, e0, g.nb[0]);
    g.nb[1] = fmaf(a, e1, g.nb[1]);
    g.nb[2] = fmaf(a, e2, g.nb[2]);
    g.nb[3] = fmaf(a, e3, g.nb[3]);
    g.nb[4] = fmaf(a, e4, g.nb[4]);
    g.nb[5] = fmaf(a, e5, g.nb[5]);
    g.nb[6] = fmaf(a, e6, g.nb[6]);
    g.nb[7] = fmaf(a, e7, g.nb[7]);
}

__global__ __launch_bounds__(256) void gat_aggr(const unsigned short* __restrict__ xl,
                                                const unsigned short* __restrict__ xr,
                                                const int* __restrict__ csr_src,
                                                const int* __restrict__ offsets,
                                                const int* __restrict__ deg,
                                                const float* __restrict__ att,
                                                const float* __restrict__ bias,
                                                const float* __restrict__ gamma,
                                                const float* __restrict__ beta,
                                                const float* __restrict__ hprev,
                                                float* __restrict__ hout,
                                                int n, int layer) {
    int wave = threadIdx.x >> 6;
    int lane = threadIdx.x & 63;
    int dst = blockIdx.x * 4 + wave;
    if (dst >= n) return;

    int lc = lane & 15;
    int eg = lane >> 4;
    int c0 = lc * 8;
    unsigned cb = (unsigned)(lc * 16);   // byte offset within a 256B row

    float4 atA = *(const float4*)&att[c0];
    float4 atB = *(const float4*)&att[c0 + 4];
    const char* xlcb = (const char*)xl + cb;   // hoisted base

    uint4 xrr = *(const uint4*)((const char*)xr + (unsigned)dst * 256u + cb);
    float4 xrA = make_float4(bflo(xrr.x), bfhi(xrr.x), bflo(xrr.y), bfhi(xrr.y));
    float4 xrB = make_float4(bflo(xrr.z), bfhi(xrr.z), bflo(xrr.w), bfhi(xrr.w));

    int start = offsets[dst];
    int cnt = deg[dst];
    const int* sp = csr_src + start;

    GatAcc g;
    g.den = 0.f;
    #pragma unroll
    for (int j = 0; j < 8; ++j) g.nb[j] = 0.f;

    for (int base = 0; base < cnt; base += 64) {
        int rem = cnt - base;
        int lim = rem < 64 ? rem : 64;
        int vidx = (lane < lim) ? sp[base + lane] : 0;
        int fq = lim >> 2;
        int q = 0;
        // 4 quads at a time: 4 gathers in flight
        for (; q + 4 <= fq; q += 4) {
            int slot = q * 4 + eg;
            int s0 = __shfl(vidx, slot);
            int s1 = __shfl(vidx, slot + 4);
            int s2 = __shfl(vidx, slot + 8);
            int s3 = __shfl(vidx, slot + 12);
            uint4 r0 = *(const uint4*)(xlcb + ((unsigned)s0 << 8));
            uint4 r1 = *(const uint4*)(xlcb + ((unsigned)s1 << 8));
            uint4 r2 = *(const uint4*)(xlcb + ((unsigned)s2 << 8));
            uint4 r3 = *(const uint4*)(xlcb + ((unsigned)s3 << 8));
            gat_edge<false>(r0, true, xrA, xrB, atA, atB, g);
            gat_edge<false>(r1, true, xrA, xrB, atA, atB, g);
            gat_edge<false>(r2, true, xrA, xrB, atA, atB, g);
            gat_edge<false>(r3, true, xrA, xrB, atA, atB, g);
        }
        for (; q < fq; ++q) {
            int slot = q * 4 + eg;
            int s0 = __shfl(vidx, slot);
            uint4 r0 = *(const uint4*)(xlcb + ((unsigned)s0 << 8));
            gat_edge<false>(r0, true, xrA, xrB, atA, atB, g);
        }
        int tail = lim & 3;
        if (tail) {
            int slot = fq * 4 + eg;     // <= 63
            int s0 = __shfl(vidx, slot);
            uint4 r0 = *(const uint4*)(xlcb + ((unsigned)s0 << 8));
            gat_edge<true>(r0, eg < tail, xrA, xrB, atA, atB, g);
        }
    }

    // merge the 4 edge groups
    g.den += __shfl_xor(g.den, 16);
    g.den += __shfl_xor(g.den, 32);
    #pragma unroll
    for (int j = 0; j < 8; ++j) {
        g.nb[j] += __shfl_xor(g.nb[j], 16);
        g.nb[j] += __shfl_xor(g.nb[j], 32);
    }

    float inv = 1.f / g.den;
    float4 bA = *(const float4*)&bias[c0];
    float4 bB = *(const float4*)&bias[c0 + 4];
    float v[8];
    v[0] = fmaf(g.nb[0], inv, bA.x);
    v[1] = fmaf(g.nb[1], inv, bA.y);
    v[2] = fmaf(g.nb[2], inv, bA.z);
    v[3] = fmaf(g.nb[3], inv, bA.w);
    v[4] = fmaf(g.nb[4], inv, bB.x);
    v[5] = fmaf(g.nb[5], inv, bB.y);
    v[6] = fmaf(g.nb[6], inv, bB.z);
    v[7] = fmaf(g.nb[7], inv, bB.w);

    float s1 = 0.f, s2 = 0.f;
    #pragma unroll
    for (int j = 0; j < 8; ++j) {
        s1 += v[j];
        s2 = fmaf(v[j], v[j], s2);
    }
    #pragma unroll
    for (int d = 1; d < 16; d <<= 1) {
        s1 += __shfl_xor(s1, d);
        s2 += __shfl_xor(s2, d);
    }
    float mu = s1 * (1.f / 128.f);
    float var = s2 * (1.f / 128.f) - mu * mu;
    float rs = rsqrtf(var + LNEPS);

    float4 gA = *(const float4*)&gamma[c0];
    float4 gB = *(const float4*)&gamma[c0 + 4];
    float4 beA = *(const float4*)&beta[c0];
    float4 beB = *(const float4*)&beta[c0 + 4];
    float y[8];
    y[0] = (v[0] - mu) * rs * gA.x + beA.x;
    y[1] = (v[1] - mu) * rs * gA.y + beA.y;
    y[2] = (v[2] - mu) * rs * gA.z + beA.z;
    y[3] = (v[3] - mu) * rs * gA.w + beA.w;
    y[4] = (v[4] - mu) * rs * gB.x + beB.x;
    y[5] = (v[5] - mu) * rs * gB.y + beB.y;
    y[6] = (v[6] - mu) * rs * gB.z + beB.z;
    y[7] = (v[7] - mu) * rs * gB.w + beB.w;

    if (layer == 2) {
        const float* hp = &hprev[(size_t)dst * HID + c0];
        float4 hA = *(const float4*)hp;
        float4 hB = *(const float4*)(hp + 4);
        y[0] += hA.x; y[1] += hA.y; y[2] += hA.z; y[3] += hA.w;
        y[4] += hB.x; y[5] += hB.y; y[6] += hB.z; y[7] += hB.w;
    }
    #pragma unroll
    for (int j = 0; j < 8; ++j)
        y[j] = (y[j] > 0.f) ? y[j] : (__expf(y[j]) - 1.f);

    if (eg == 0) {
        float* op = &hout[(size_t)dst * HID + c0];
        *(float4*)op = make_float4(y[0], y[1], y[2], y[3]);
        *(float4*)(op + 4) = make_float4(y[4], y[5], y[6], y[7]);
    }
}

// ---------------- fused prediction + uncertainty heads (register-blocked GEMM) ----------------
__global__ __launch_bounds__(256) void k_heads(const float* __restrict__ hf,
                                               const float* __restrict__ Wp1, const float* __restrict__ bp1,
                                               const float* __restrict__ Wp2, const float* __restrict__ bp2,
                                               const float* __restrict__ Wu1, const float* __restrict__ bu1,
                                               const float* __restrict__ Wu2, const float* __restrict__ bu2,
                                               float* __restrict__ out, int n) {
    __shared__ float sXH[64 * 132];
    __shared__ float sW[32 * 96];
    __shared__ float sW2[64 * 6 + 32 * 6];
    int tid = threadIdx.x;
    int node0 = blockIdx.x * 64;

    for (int i = tid; i < 576; i += 256) sW2[i] = (i < 384) ? Wp2[i] : Wu2[i - 384];

    {
        int row = tid >> 2, seg = tid & 3;
        int gn = node0 + row;
        const float* src = &hf[(size_t)gn * HID + seg * 32];
        float* dst = &sXH[row * 132 + seg * 32];
        #pragma unroll
        for (int q = 0; q < 8; ++q) {
            float4 v = make_float4(0.f, 0.f, 0.f, 0.f);
            if (gn < n) v = *(const float4*)&src[q * 4];
            *(float4*)&dst[q * 4] = v;
        }
    }

    int cg = tid & 15;
    int ng = tid >> 4;
    int c0 = cg * 6;

    float acc[4][6];
    #pragma unroll
    for (int i = 0; i < 4; ++i)
        #pragma unroll
        for (int j = 0; j < 6; ++j) acc[i][j] = 0.f;

    for (int kc = 0; kc < HID; kc += 32) {
        __syncthreads();
        #pragma unroll
        for (int q = 0; q < 3; ++q) {
            int g = q * 256 + tid;
            int r = g / 24, c4 = g % 24;
            int c = c4 * 4;
            const float* src = (c < 64) ? &Wp1[(size_t)(kc + r) * 64 + c]
                                        : &Wu1[(size_t)(kc + r) * 32 + (c - 64)];
            *(float4*)&sW[r * 96 + c] = *(const float4*)src;
        }
        __syncthreads();
        #pragma unroll
        for (int k = 0; k < 32; ++k) {
            const float* wr = &sW[k * 96 + c0];
            float w0 = wr[0], w1 = wr[1], w2 = wr[2], w3 = wr[3], w4 = wr[4], w5 = wr[5];
            #pragma unroll
            for (int i = 0; i < 4; ++i) {
                float xv = sXH[(ng * 4 + i) * 132 + kc + k];
                acc[i][0] = fmaf(xv, w0, acc[i][0]);
                acc[i][1] = fmaf(xv, w1, acc[i][1]);
                acc[i][2] = fmaf(xv, w2, acc[i][2]);
                acc[i][3] = fmaf(xv, w3, acc[i][3]);
                acc[i][4] = fmaf(xv, w4, acc[i][4]);
                acc[i][5] = fmaf(xv, w5, acc[i][5]);
            }
        }
    }

    __syncthreads();
    float bv[6];
    #pragma unroll
    for (int j = 0; j < 6; ++j) {
        int c = c0 + j;
        bv[j] = (c < 64) ? bp1[c] : bu1[c - 64];
    }
    #pragma unroll
    for (int i = 0; i < 4; ++i) {
        int row = ng * 4 + i;
        #pragma unroll
        for (int j = 0; j < 6; ++j) {
            float v = acc[i][j] + bv[j];
            sXH[row * 97 + c0 + j] = fmaxf(v, 0.f);
        }
    }
    __syncthreads();

    int nl = tid & 63;
    int g = tid >> 6;
    int node = node0 + nl;
    float a0 = 0.f, a1 = 0.f, a2 = 0.f;
    if (g < 2) {
        int j0 = 3 * g;
        const float* hrow = &sXH[nl * 97];
        #pragma unroll 8
        for (int k = 0; k < 64; ++k) {
            float hv = hrow[k];
            a0 = fmaf(hv, sW2[k * 6 + j0], a0);
            a1 = fmaf(hv, sW2[k * 6 + j0 + 1], a1);
            a2 = fmaf(hv, sW2[k * 6 + j0 + 2], a2);
        }
        if (node < n) {
            size_t pb = (size_t)node * 6 + j0;
            out[pb]     = a0 + bp2[j0];
            out[pb + 1] = a1 + bp2[j0 + 1];
            out[pb + 2] = a2 + bp2[j0 + 2];
        }
    } else {
        int j0 = 3 * (g - 2);
        const float* hrow = &sXH[nl * 97 + 64];
        #pragma unroll 8
        for (int k = 0; k < 32; ++k) {
            float hv = hrow[k];
            a0 = fmaf(hv, sW2[384 + k * 6 + j0], a0);
            a1 = fmaf(hv, sW2[384 + k * 6 + j0 + 1], a1);
            a2 = fmaf(hv, sW2[384 + k * 6 + j0 + 2], a2);
        }
        if (node < n) {
            float z0 = a0 + bu2[j0], z1 = a1 + bu2[j0 + 1], z2 = a2 + bu2[j0 + 2];
            size_t ub = (size_t)n * 6 + (size_t)node * 6 + j0;
            out[ub]     = fmaxf(z0, 0.f) + log1pf(__expf(-fabsf(z0)));
            out[ub + 1] = fmaxf(z1, 0.f) + log1pf(__expf(-fabsf(z1)));
            out[ub + 2] = fmaxf(z2, 0.f) + log1pf(__expf(-fabsf(z2)));
        }
    }
}

// ---------------- launch ----------------

extern "C" void kernel_launch(void* const* d_in, const int* in_sizes, int n_in,
                              void* d_out, int out_size, void* d_ws, size_t ws_size,
                              hipStream_t stream) {
    const float* x   = (const float*)d_in[0];
    const int*   ei  = (const int*)d_in[1];
    const float* Wl1 = (const float*)d_in[2];
    const float* Wr1 = (const float*)d_in[3];
    const float* att1 = (const float*)d_in[4];
    const float* bias1 = (const float*)d_in[5];
    const float* g1 = (const float*)d_in[6];
    const float* b1 = (const float*)d_in[7];
    const float* Wl2 = (const float*)d_in[8];
    const float* Wr2 = (const float*)d_in[9];
    const float* att2 = (const float*)d_in[10];
    const float* bias2 = (const float*)d_in[11];
    const float* g2 = (const float*)d_in[12];
    const float* b2 = (const float*)d_in[13];
    const float* Wp1 = (const float*)d_in[14];
    const float* bp1 = (const float*)d_in[15];
    const float* Wp2 = (const float*)d_in[16];
    const float* bp2 = (const float*)d_in[17];
    const float* Wu1 = (const float*)d_in[18];
    const float* bu1 = (const float*)d_in[19];
    const float* Wu2 = (const float*)d_in[20];
    const float* bu2 = (const float*)d_in[21];

    int N_ = in_sizes[0] / 32;
    int E_ = in_sizes[1] / 2;
    int EA = E_ + N_;

    // workspace layout
    char* p = (char*)d_ws;
    size_t fbytes = (size_t)N_ * HID * sizeof(float);
    unsigned short* xl = (unsigned short*)p; p += fbytes / 2;  // bf16
    unsigned short* xr = (unsigned short*)p; p += fbytes / 2;  // bf16
    float* h  = (float*)p; p += fbytes;
    float* hf = (float*)p; p += fbytes;
    auto align16 = [](size_t s) { return (s + 15) & ~(size_t)15; };
    int* deg     = (int*)p; p += align16((size_t)N_ * 4);
    int* offsets = (int*)p; p += align16((size_t)N_ * 4);
    int* bsum    = (int*)p; p += 64 * 4;
    int* csr_src = (int*)p; p += align16((size_t)EA * 4);
    // epos aliases hf: dead before gat layer-2 writes hf
    int* epos = (int*)hf;

    int nScan = cdiv(N_, 1024);
    k_init_deg<<<cdiv(N_, 256), 256, 0, stream>>>(deg, N_);
    k_count_rank<<<cdiv(E_, 256), 256, 0, stream>>>(ei, E_, deg, epos);
    k_scan1<<<nScan, 1024, 0, stream>>>(deg, N_, offsets, bsum);
    k_scan2<<<1, 64, 0, stream>>>(bsum, nScan);
    k_scan3<<<nScan, 1024, 0, stream>>>(offsets, bsum, N_, csr_src);
    k_scatter<<<cdiv(E_, 256), 256, 0, stream>>>(ei, epos, offsets, E_, csr_src);

    // layer 1
    dual_linear<32><<<cdiv(N_, 32), 128, 0, stream>>>(x, Wl1, Wr1, xl, xr, N_);
    gat_aggr<<<cdiv(N_, 4), 256, 0, stream>>>(xl, xr, csr_src, offsets, deg,
                                              att1, bias1, g1, b1, nullptr, h, N_, 1);
    // layer 2
    dual_linear<128><<<cdiv(N_, 32), 128, 0, stream>>>(h, Wl2, Wr2, xl, xr, N_);
    gat_aggr<<<cdiv(N_, 4), 256, 0, stream>>>(xl, xr, csr_src, offsets, deg,
                                              att2, bias2, g2, b2, h, hf, N_, 2);
    // heads
    k_heads<<<cdiv(N_, 64), 256, 0, stream>>>(hf, Wp1, bp1, Wp2, bp2,
                                              Wu1, bu1, Wu2, bu2, (float*)d_out, N_);
}

// Round 11
// 324.286 us; speedup vs baseline: 1.1737x; 1.1737x over previous
//
#include <hip/hip_runtime.h>
#include <hip/hip_bf16.h>
#include <math.h>

#define HID 128
#define HEADS 4
#define CH 32
#define OUTD 6
#define SLOPE 0.2f
#define LNEPS 1e-5f

static inline int cdiv(int a, int b) { return (a + b - 1) / b; }

typedef __bf16 bf16x8 __attribute__((ext_vector_type(8)));
typedef float f32x4 __attribute__((ext_vector_type(4)));

__device__ __forceinline__ unsigned short f2bf(float f) {
    unsigned int u = __builtin_bit_cast(unsigned int, f);
    u += 0x7FFFu + ((u >> 16) & 1u);   // round-to-nearest-even
    return (unsigned short)(u >> 16);
}
__device__ __forceinline__ float bflo(unsigned int u) {
    return __builtin_bit_cast(float, u << 16);
}
__device__ __forceinline__ float bfhi(unsigned int u) {
    return __builtin_bit_cast(float, u & 0xFFFF0000u);
}

// ---------------- CSR build ----------------
// deg starts at 1: the self-loop of node i owns rank 0 (scattered in fused scan3).

__global__ void k_init_deg(int* __restrict__ deg, int n) {
    int i = blockIdx.x * 256 + threadIdx.x;
    if (i < n) deg[i] = 1;
}

__global__ void k_count_rank(const int* __restrict__ ei, int E,
                             int* __restrict__ deg, int* __restrict__ epos) {
    int e = blockIdx.x * 256 + threadIdx.x;
    if (e >= E) return;
    int dst = ei[E + e];
    epos[e] = atomicAdd(&deg[dst], 1);
}

__global__ __launch_bounds__(1024) void k_scan1(const int* __restrict__ deg, int n,
                                                int* __restrict__ ex, int* __restrict__ bsum) {
    __shared__ int sw[16];
    int i = blockIdx.x * 1024 + threadIdx.x;
    int v = (i < n) ? deg[i] : 0;
    int lane = threadIdx.x & 63, w = threadIdx.x >> 6;
    int x = v;
    #pragma unroll
    for (int d = 1; d < 64; d <<= 1) {
        int t = __shfl_up(x, d);
        if (lane >= d) x += t;
    }
    if (lane == 63) sw[w] = x;
    __syncthreads();
    if (w == 0) {
        int t = (lane < 16) ? sw[lane] : 0;
        #pragma unroll
        for (int d = 1; d < 16; d <<= 1) {
            int u = __shfl_up(t, d);
            if (lane >= d) t += u;
        }
        if (lane < 16) sw[lane] = t;
    }
    __syncthreads();
    int woff = (w > 0) ? sw[w - 1] : 0;
    int incl = x + woff;
    if (i < n) ex[i] = incl - v;
    if (threadIdx.x == 1023) bsum[blockIdx.x] = incl;
}

__global__ void k_scan2(int* __restrict__ bsum, int nb) {
    int lane = threadIdx.x;
    int v = (lane < nb) ? bsum[lane] : 0;
    int x = v;
    #pragma unroll
    for (int d = 1; d < 64; d <<= 1) {
        int t = __shfl_up(x, d);
        if (lane >= d) x += t;
    }
    if (lane < nb) bsum[lane] = x - v;
}

__global__ __launch_bounds__(1024) void k_scan3(int* __restrict__ ex, const int* __restrict__ bsum,
                                                int n, int* __restrict__ csr_src) {
    int i = blockIdx.x * 1024 + threadIdx.x;
    if (i < n) {
        int off = ex[i] + bsum[blockIdx.x];
        ex[i] = off;
        csr_src[off] = i;
    }
}

__global__ void k_scatter(const int* __restrict__ ei, const int* __restrict__ epos,
                          const int* __restrict__ offsets, int E,
                          int* __restrict__ csr_src) {
    int e = blockIdx.x * 256 + threadIdx.x;
    if (e >= E) return;
    int src = ei[e], dst = ei[E + e];
    csr_src[offsets[dst] + epos[e]] = src;
}

// ---------------- W pre-convert: [K][128]x2 f32 -> Wb[kb][c][8] bf16 ----------------
__global__ void k_wconv(const float* __restrict__ Wl, const float* __restrict__ Wr,
                        unsigned short* __restrict__ Wb, int K) {
    int i = blockIdx.x * 256 + threadIdx.x;
    if (i >= K * 256) return;
    int kk = i & 7, c = (i >> 3) & 255, kb = i >> 11;
    int k = kb * 8 + kk;
    float v = (c < 128) ? Wl[k * 128 + c] : Wr[k * 128 + (c - 128)];
    Wb[i] = f2bf(v);
}

// ---------------- dual linear via MFMA: [outL|outR] = X @ [Wl|Wr], bf16 out ----------------
// 64 nodes x 256 cols per block, 4 waves; wave w owns cols [64w, 64w+64).
// X staged once to LDS bf16 (stride K+8). B-frags from Wb (coalesced 16B/lane).
// mfma_f32_16x16x32_bf16: A row=lane&15,k=(lane>>4)*8+j ; B col=lane&15 ;
// D col=lane&15,row=(lane>>4)*4+reg. Epilogue restaged via LDS (stride 264)
// for fully-coalesced bf16x8 stores.
template <int K>
__global__ __launch_bounds__(256) void dual_linear_mfma(const float* __restrict__ X,
                                                        const unsigned short* __restrict__ Wb,
                                                        unsigned short* __restrict__ outL,
                                                        unsigned short* __restrict__ outR, int n) {
    constexpr int INS = K + 8;                 // in-stage row stride (ushorts)
    __shared__ unsigned short buf[64 * 264];   // 33.8 KB, in-stage union out-stage
    int tid = threadIdx.x;
    int lane = tid & 63;
    int w = tid >> 6;
    int n0 = blockIdx.x * 64;

    // stage-in: 64 rows x K f32 -> bf16 LDS
    constexpr int F4R = K / 4;                 // float4 per row
    constexpr int ITS = 64 * F4R / 256;
    #pragma unroll
    for (int it = 0; it < ITS; ++it) {
        int f = it * 256 + tid;
        int row = f / F4R, c4 = f % F4R;
        int gn = n0 + row;
        float4 v = make_float4(0.f, 0.f, 0.f, 0.f);
        if (gn < n) v = *(const float4*)&X[(size_t)gn * K + c4 * 4];
        ushort4 o;
        o.x = f2bf(v.x); o.y = f2bf(v.y); o.z = f2bf(v.z); o.w = f2bf(v.w);
        *(ushort4*)&buf[row * INS + c4 * 4] = o;
    }
    __syncthreads();

    int l15 = lane & 15, l4 = lane >> 4;
    int c0 = w * 64;

    f32x4 acc[4][4];
    #pragma unroll
    for (int rt = 0; rt < 4; ++rt)
        #pragma unroll
        for (int ct = 0; ct < 4; ++ct)
            acc[rt][ct] = (f32x4)(0.f);

    #pragma unroll
    for (int ks = 0; ks < K / 32; ++ks) {
        bf16x8 a[4], b[4];
        #pragma unroll
        for (int rt = 0; rt < 4; ++rt)
            a[rt] = *(const bf16x8*)&buf[(rt * 16 + l15) * INS + ks * 32 + l4 * 8];
        #pragma unroll
        for (int ct = 0; ct < 4; ++ct)
            b[ct] = *(const bf16x8*)&Wb[(((ks * 4 + l4) * 256) + (c0 + ct * 16 + l15)) * 8];
        #pragma unroll
        for (int rt = 0; rt < 4; ++rt)
            #pragma unroll
            for (int ct = 0; ct < 4; ++ct)
                acc[rt][ct] = __builtin_amdgcn_mfma_f32_16x16x32_bf16(a[rt], b[ct], acc[rt][ct], 0, 0, 0);
    }
    __syncthreads();

    // epilogue: scatter acc to out-stage [64][264]
    #pragma unroll
    for (int rt = 0; rt < 4; ++rt)
        #pragma unroll
        for (int ct = 0; ct < 4; ++ct)
            #pragma unroll
            for (int j = 0; j < 4; ++j)
                buf[(rt * 16 + l4 * 4 + j) * 264 + c0 + ct * 16 + l15] = f2bf(acc[rt][ct][j]);
    __syncthreads();

    // copy out: 64 rows x 256 cols bf16, coalesced 16B stores
    #pragma unroll
    for (int it = 0; it < 8; ++it) {
        int f = it * 256 + tid;
        int row = f >> 5, cw = f & 31;
        int gn = n0 + row;
        if (gn < n) {
            uint4 v = *(const uint4*)&buf[row * 264 + cw * 8];
            if (cw < 16) *(uint4*)&outL[(size_t)gn * 128 + cw * 8] = v;
            else         *(uint4*)&outR[(size_t)gn * 128 + (cw - 16) * 8] = v;
        }
    }
}

// ---------------- GATv2 aggregation with fused LN(+residual)+ELU epilogue ----------------
// round-8 proven form: lane lc=lane&15 owns 8 channels (head=lc>>2), eg=lane>>4
// edge slot, 2-deep prefetch, check-free full quads + single masked tail.

struct GatAcc {
    float den;
    float nb[8];
};

template <bool CHECKED>
__device__ __forceinline__ void gat_edge(uint4 r, bool valid,
                                         const float4& xrA, const float4& xrB,
                                         const float4& atA, const float4& atB,
                                         GatAcc& g) {
    float e0 = bflo(r.x), e1 = bfhi(r.x);
    float e2 = bflo(r.y), e3 = bfhi(r.y);
    float e4 = bflo(r.z), e5 = bfhi(r.z);
    float e6 = bflo(r.w), e7 = bfhi(r.w);
    float v0 = e0 + xrA.x; v0 = fmaxf(v0, SLOPE * v0);
    float v1 = e1 + xrA.y; v1 = fmaxf(v1, SLOPE * v1);
    float v2 = e2 + xrA.z; v2 = fmaxf(v2, SLOPE * v2);
    float v3 = e3 + xrA.w; v3 = fmaxf(v3, SLOPE * v3);
    float v4 = e4 + xrB.x; v4 = fmaxf(v4, SLOPE * v4);
    float v5 = e5 + xrB.y; v5 = fmaxf(v5, SLOPE * v5);
    float v6 = e6 + xrB.z; v6 = fmaxf(v6, SLOPE * v6);
    float v7 = e7 + xrB.w; v7 = fmaxf(v7, SLOPE * v7);
    float t = v0 * atA.x;
    t = fmaf(v1, atA.y, t);
    t = fmaf(v2, atA.z, t);
    t = fmaf(v3, atA.w, t);
    t = fmaf(v4, atB.x, t);
    t = fmaf(v5, atB.y, t);
    t = fmaf(v6, atB.z, t);
    t = fmaf(v7, atB.w, t);
    t += __shfl_xor(t, 1);
    t += __shfl_xor(t, 2);
    float a = __expf(t);
    if (CHECKED) a = valid ? a : 0.f;
    g.den += a;
    g.nb[0] = fmaf(a, e0, g.nb[0]);
    g.nb[1] = fmaf(a, e1, g.nb[1]);
    g.nb[2] = fmaf(a, e2, g.nb[2]);
    g.nb[3] = fmaf(a, e3, g.nb[3]);
    g.nb[4] = fmaf(a, e4, g.nb[4]);
    g.nb[5] = fmaf(a, e5, g.nb[5]);
    g.nb[6] = fmaf(a, e6, g.nb[6]);
    g.nb[7] = fmaf(a, e7, g.nb[7]);
}

__global__ __launch_bounds__(256) void gat_aggr(const unsigned short* __restrict__ xl,
                                                const unsigned short* __restrict__ xr,
                                                const int* __restrict__ csr_src,
                                                const int* __restrict__ offsets,
                                                const int* __restrict__ deg,
                                                const float* __restrict__ att,
                                                const float* __restrict__ bias,
                                                const float* __restrict__ gamma,
                                                const float* __restrict__ beta,
                                                const float* __restrict__ hprev,
                                                float* __restrict__ hout,
                                                int n, int layer) {
    int wave = threadIdx.x >> 6;
    int lane = threadIdx.x & 63;
    int dst = blockIdx.x * 4 + wave;
    if (dst >= n) return;

    int lc = lane & 15;
    int eg = lane >> 4;
    int c0 = lc * 8;
    unsigned cb = (unsigned)(lc * 16);

    float4 atA = *(const float4*)&att[c0];
    float4 atB = *(const float4*)&att[c0 + 4];
    const char* xlb = (const char*)xl;

    uint4 xrr = *(const uint4*)((const char*)xr + (unsigned)dst * 256u + cb);
    float4 xrA = make_float4(bflo(xrr.x), bfhi(xrr.x), bflo(xrr.y), bfhi(xrr.y));
    float4 xrB = make_float4(bflo(xrr.z), bfhi(xrr.z), bflo(xrr.w), bfhi(xrr.w));

    int start = offsets[dst];
    int cnt = deg[dst];
    const int* sp = csr_src + start;

    GatAcc g;
    g.den = 0.f;
    #pragma unroll
    for (int j = 0; j < 8; ++j) g.nb[j] = 0.f;

    for (int base = 0; base < cnt; base += 64) {
        int rem = cnt - base;
        int lim = rem < 64 ? rem : 64;
        int vidx = (lane < lim) ? sp[base + lane] : 0;
        int fq = lim >> 2;
        int q = 0;
        for (; q + 2 <= fq; q += 2) {
            int slot0 = q * 4 + eg;
            int s0 = __shfl(vidx, slot0);
            int s1 = __shfl(vidx, slot0 + 4);
            uint4 r0 = *(const uint4*)(xlb + (((unsigned)s0 << 8) + cb));
            uint4 r1 = *(const uint4*)(xlb + (((unsigned)s1 << 8) + cb));
            gat_edge<false>(r0, true, xrA, xrB, atA, atB, g);
            gat_edge<false>(r1, true, xrA, xrB, atA, atB, g);
        }
        if (q < fq) {
            int slot0 = q * 4 + eg;
            int s0 = __shfl(vidx, slot0);
            uint4 r0 = *(const uint4*)(xlb + (((unsigned)s0 << 8) + cb));
            gat_edge<false>(r0, true, xrA, xrB, atA, atB, g);
        }
        int tail = lim & 3;
        if (tail) {
            int slot0 = fq * 4 + eg;
            int s0 = __shfl(vidx, slot0);
            uint4 r0 = *(const uint4*)(xlb + (((unsigned)s0 << 8) + cb));
            gat_edge<true>(r0, eg < tail, xrA, xrB, atA, atB, g);
        }
    }

    g.den += __shfl_xor(g.den, 16);
    g.den += __shfl_xor(g.den, 32);
    #pragma unroll
    for (int j = 0; j < 8; ++j) {
        g.nb[j] += __shfl_xor(g.nb[j], 16);
        g.nb[j] += __shfl_xor(g.nb[j], 32);
    }

    float inv = 1.f / g.den;
    float4 bA = *(const float4*)&bias[c0];
    float4 bB = *(const float4*)&bias[c0 + 4];
    float v[8];
    v[0] = fmaf(g.nb[0], inv, bA.x);
    v[1] = fmaf(g.nb[1], inv, bA.y);
    v[2] = fmaf(g.nb[2], inv, bA.z);
    v[3] = fmaf(g.nb[3], inv, bA.w);
    v[4] = fmaf(g.nb[4], inv, bB.x);
    v[5] = fmaf(g.nb[5], inv, bB.y);
    v[6] = fmaf(g.nb[6], inv, bB.z);
    v[7] = fmaf(g.nb[7], inv, bB.w);

    float s1 = 0.f, s2 = 0.f;
    #pragma unroll
    for (int j = 0; j < 8; ++j) {
        s1 += v[j];
        s2 = fmaf(v[j], v[j], s2);
    }
    #pragma unroll
    for (int d = 1; d < 16; d <<= 1) {
        s1 += __shfl_xor(s1, d);
        s2 += __shfl_xor(s2, d);
    }
    float mu = s1 * (1.f / 128.f);
    float var = s2 * (1.f / 128.f) - mu * mu;
    float rs = rsqrtf(var + LNEPS);

    float4 gA = *(const float4*)&gamma[c0];
    float4 gB = *(const float4*)&gamma[c0 + 4];
    float4 beA = *(const float4*)&beta[c0];
    float4 beB = *(const float4*)&beta[c0 + 4];
    float y[8];
    y[0] = (v[0] - mu) * rs * gA.x + beA.x;
    y[1] = (v[1] - mu) * rs * gA.y + beA.y;
    y[2] = (v[2] - mu) * rs * gA.z + beA.z;
    y[3] = (v[3] - mu) * rs * gA.w + beA.w;
    y[4] = (v[4] - mu) * rs * gB.x + beB.x;
    y[5] = (v[5] - mu) * rs * gB.y + beB.y;
    y[6] = (v[6] - mu) * rs * gB.z + beB.z;
    y[7] = (v[7] - mu) * rs * gB.w + beB.w;

    if (layer == 2) {
        const float* hp = &hprev[(size_t)dst * HID + c0];
        float4 hA = *(const float4*)hp;
        float4 hB = *(const float4*)(hp + 4);
        y[0] += hA.x; y[1] += hA.y; y[2] += hA.z; y[3] += hA.w;
        y[4] += hB.x; y[5] += hB.y; y[6] += hB.z; y[7] += hB.w;
    }
    #pragma unroll
    for (int j = 0; j < 8; ++j)
        y[j] = (y[j] > 0.f) ? y[j] : (__expf(y[j]) - 1.f);

    if (eg == 0) {
        float* op = &hout[(size_t)dst * HID + c0];
        *(float4*)op = make_float4(y[0], y[1], y[2], y[3]);
        *(float4*)(op + 4) = make_float4(y[4], y[5], y[6], y[7]);
    }
}

// ---------------- fused prediction + uncertainty heads (register-blocked GEMM) ----------------
__global__ __launch_bounds__(256) void k_heads(const float* __restrict__ hf,
                                               const float* __restrict__ Wp1, const float* __restrict__ bp1,
                                               const float* __restrict__ Wp2, const float* __restrict__ bp2,
                                               const float* __restrict__ Wu1, const float* __restrict__ bu1,
                                               const float* __restrict__ Wu2, const float* __restrict__ bu2,
                                               float* __restrict__ out, int n) {
    __shared__ float sXH[64 * 132];
    __shared__ float sW[32 * 96];
    __shared__ float sW2[64 * 6 + 32 * 6];
    int tid = threadIdx.x;
    int node0 = blockIdx.x * 64;

    for (int i = tid; i < 576; i += 256) sW2[i] = (i < 384) ? Wp2[i] : Wu2[i - 384];

    {
        int row = tid >> 2, seg = tid & 3;
        int gn = node0 + row;
        const float* src = &hf[(size_t)gn * HID + seg * 32];
        float* dst = &sXH[row * 132 + seg * 32];
        #pragma unroll
        for (int q = 0; q < 8; ++q) {
            float4 v = make_float4(0.f, 0.f, 0.f, 0.f);
            if (gn < n) v = *(const float4*)&src[q * 4];
            *(float4*)&dst[q * 4] = v;
        }
    }

    int cg = tid & 15;
    int ng = tid >> 4;
    int c0 = cg * 6;

    float acc[4][6];
    #pragma unroll
    for (int i = 0; i < 4; ++i)
        #pragma unroll
        for (int j = 0; j < 6; ++j) acc[i][j] = 0.f;

    for (int kc = 0; kc < HID; kc += 32) {
        __syncthreads();
        #pragma unroll
        for (int q = 0; q < 3; ++q) {
            int g = q * 256 + tid;
            int r = g / 24, c4 = g % 24;
            int c = c4 * 4;
            const float* src = (c < 64) ? &Wp1[(size_t)(kc + r) * 64 + c]
                                        : &Wu1[(size_t)(kc + r) * 32 + (c - 64)];
            *(float4*)&sW[r * 96 + c] = *(const float4*)src;
        }
        __syncthreads();
        #pragma unroll
        for (int k = 0; k < 32; ++k) {
            const float* wr = &sW[k * 96 + c0];
            float w0 = wr[0], w1 = wr[1], w2 = wr[2], w3 = wr[3], w4 = wr[4], w5 = wr[5];
            #pragma unroll
            for (int i = 0; i < 4; ++i) {
                float xv = sXH[(ng * 4 + i) * 132 + kc + k];
                acc[i][0] = fmaf(xv, w0, acc[i][0]);
                acc[i][1] = fmaf(xv, w1, acc[i][1]);
                acc[i][2] = fmaf(xv, w2, acc[i][2]);
                acc[i][3] = fmaf(xv, w3, acc[i][3]);
                acc[i][4] = fmaf(xv, w4, acc[i][4]);
                acc[i][5] = fmaf(xv, w5, acc[i][5]);
            }
        }
    }

    __syncthreads();
    float bv[6];
    #pragma unroll
    for (int j = 0; j < 6; ++j) {
        int c = c0 + j;
        bv[j] = (c < 64) ? bp1[c] : bu1[c - 64];
    }
    #pragma unroll
    for (int i = 0; i < 4; ++i) {
        int row = ng * 4 + i;
        #pragma unroll
        for (int j = 0; j < 6; ++j) {
            float v = acc[i][j] + bv[j];
            sXH[row * 97 + c0 + j] = fmaxf(v, 0.f);
        }
    }
    __syncthreads();

    int nl = tid & 63;
    int g = tid >> 6;
    int node = node0 + nl;
    float a0 = 0.f, a1 = 0.f, a2 = 0.f;
    if (g < 2) {
        int j0 = 3 * g;
        const float* hrow = &sXH[nl * 97];
        #pragma unroll 8
        for (int k = 0; k < 64; ++k) {
            float hv = hrow[k];
            a0 = fmaf(hv, sW2[k * 6 + j0], a0);
            a1 = fmaf(hv, sW2[k * 6 + j0 + 1], a1);
            a2 = fmaf(hv, sW2[k * 6 + j0 + 2], a2);
        }
        if (node < n) {
            size_t pb = (size_t)node * 6 + j0;
            out[pb]     = a0 + bp2[j0];
            out[pb + 1] = a1 + bp2[j0 + 1];
            out[pb + 2] = a2 + bp2[j0 + 2];
        }
    } else {
        int j0 = 3 * (g - 2);
        const float* hrow = &sXH[nl * 97 + 64];
        #pragma unroll 8
        for (int k = 0; k < 32; ++k) {
            float hv = hrow[k];
            a0 = fmaf(hv, sW2[384 + k * 6 + j0], a0);
            a1 = fmaf(hv, sW2[384 + k * 6 + j0 + 1], a1);
            a2 = fmaf(hv, sW2[384 + k * 6 + j0 + 2], a2);
        }
        if (node < n) {
            float z0 = a0 + bu2[j0], z1 = a1 + bu2[j0 + 1], z2 = a2 + bu2[j0 + 2];
            size_t ub = (size_t)n * 6 + (size_t)node * 6 + j0;
            out[ub]     = fmaxf(z0, 0.f) + log1pf(__expf(-fabsf(z0)));
            out[ub + 1] = fmaxf(z1, 0.f) + log1pf(__expf(-fabsf(z1)));
            out[ub + 2] = fmaxf(z2, 0.f) + log1pf(__expf(-fabsf(z2)));
        }
    }
}

// ---------------- launch ----------------

extern "C" void kernel_launch(void* const* d_in, const int* in_sizes, int n_in,
                              void* d_out, int out_size, void* d_ws, size_t ws_size,
                              hipStream_t stream) {
    const float* x   = (const float*)d_in[0];
    const int*   ei  = (const int*)d_in[1];
    const float* Wl1 = (const float*)d_in[2];
    const float* Wr1 = (const float*)d_in[3];
    const float* att1 = (const float*)d_in[4];
    const float* bias1 = (const float*)d_in[5];
    const float* g1 = (const float*)d_in[6];
    const float* b1 = (const float*)d_in[7];
    const float* Wl2 = (const float*)d_in[8];
    const float* Wr2 = (const float*)d_in[9];
    const float* att2 = (const float*)d_in[10];
    const float* bias2 = (const float*)d_in[11];
    const float* g2 = (const float*)d_in[12];
    const float* b2 = (const float*)d_in[13];
    const float* Wp1 = (const float*)d_in[14];
    const float* bp1 = (const float*)d_in[15];
    const float* Wp2 = (const float*)d_in[16];
    const float* bp2 = (const float*)d_in[17];
    const float* Wu1 = (const float*)d_in[18];
    const float* bu1 = (const float*)d_in[19];
    const float* Wu2 = (const float*)d_in[20];
    const float* bu2 = (const float*)d_in[21];

    int N_ = in_sizes[0] / 32;
    int E_ = in_sizes[1] / 2;
    int EA = E_ + N_;

    // workspace layout
    char* p = (char*)d_ws;
    size_t fbytes = (size_t)N_ * HID * sizeof(float);
    unsigned short* xl = (unsigned short*)p; p += fbytes / 2;  // bf16
    unsigned short* xr = (unsigned short*)p; p += fbytes / 2;  // bf16
    float* h  = (float*)p; p += fbytes;
    float* hf = (float*)p; p += fbytes;
    auto align16 = [](size_t s) { return (s + 15) & ~(size_t)15; };
    int* deg     = (int*)p; p += align16((size_t)N_ * 4);
    int* offsets = (int*)p; p += align16((size_t)N_ * 4);
    int* bsum    = (int*)p; p += 64 * 4;
    int* csr_src = (int*)p; p += align16((size_t)EA * 4);
    unsigned short* Wb1 = (unsigned short*)p; p += 32 * 256 * 2;
    unsigned short* Wb2 = (unsigned short*)p; p += 128 * 256 * 2;
    // epos aliases hf: dead before gat layer-2 writes hf
    int* epos = (int*)hf;

    int nScan = cdiv(N_, 1024);
    k_init_deg<<<cdiv(N_, 256), 256, 0, stream>>>(deg, N_);
    k_count_rank<<<cdiv(E_, 256), 256, 0, stream>>>(ei, E_, deg, epos);
    k_scan1<<<nScan, 1024, 0, stream>>>(deg, N_, offsets, bsum);
    k_scan2<<<1, 64, 0, stream>>>(bsum, nScan);
    k_scan3<<<nScan, 1024, 0, stream>>>(offsets, bsum, N_, csr_src);
    k_scatter<<<cdiv(E_, 256), 256, 0, stream>>>(ei, epos, offsets, E_, csr_src);

    k_wconv<<<cdiv(32 * 256, 256), 256, 0, stream>>>(Wl1, Wr1, Wb1, 32);
    k_wconv<<<cdiv(128 * 256, 256), 256, 0, stream>>>(Wl2, Wr2, Wb2, 128);

    // layer 1
    dual_linear_mfma<32><<<cdiv(N_, 64), 256, 0, stream>>>(x, Wb1, xl, xr, N_);
    gat_aggr<<<cdiv(N_, 4), 256, 0, stream>>>(xl, xr, csr_src, offsets, deg,
                                              att1, bias1, g1, b1, nullptr, h, N_, 1);
    // layer 2
    dual_linear_mfma<128><<<cdiv(N_, 64), 256, 0, stream>>>(h, Wb2, xl, xr, N_);
    gat_aggr<<<cdiv(N_, 4), 256, 0, stream>>>(xl, xr, csr_src, offsets, deg,
                                              att2, bias2, g2, b2, h, hf, N_, 2);
    // heads
    k_heads<<<cdiv(N_, 64), 256, 0, stream>>>(hf, Wp1, bp1, Wp2, bp2,
                                              Wu1, bu1, Wu2, bu2, (float*)d_out, N_);
}

// Round 12
// 322.243 us; speedup vs baseline: 1.1812x; 1.0063x over previous
//
#include <hip/hip_runtime.h>
#include <hip/hip_bf16.h>
#include <math.h>

#define HID 128
#define HEADS 4
#define CH 32
#define OUTD 6
#define SLOPE 0.2f
#define LNEPS 1e-5f

static inline int cdiv(int a, int b) { return (a + b - 1) / b; }

typedef __bf16 bf16x8 __attribute__((ext_vector_type(8)));
typedef float f32x4 __attribute__((ext_vector_type(4)));

__device__ __forceinline__ unsigned short f2bf(float f) {
    unsigned int u = __builtin_bit_cast(unsigned int, f);
    u += 0x7FFFu + ((u >> 16) & 1u);   // round-to-nearest-even
    return (unsigned short)(u >> 16);
}
__device__ __forceinline__ float bflo(unsigned int u) {
    return __builtin_bit_cast(float, u << 16);
}
__device__ __forceinline__ float bfhi(unsigned int u) {
    return __builtin_bit_cast(float, u & 0xFFFF0000u);
}

// ---------------- setup: deg init + W pre-convert (both layers), one launch ----------------
// Wb layout: [kb][c(0..255)][kk(0..7)] bf16, c<128 -> Wl col, else Wr col.
__global__ void k_setup(int* __restrict__ deg, int n,
                        const float* __restrict__ Wl1, const float* __restrict__ Wr1,
                        unsigned short* __restrict__ Wb1,
                        const float* __restrict__ Wl2, const float* __restrict__ Wr2,
                        unsigned short* __restrict__ Wb2) {
    int g = blockIdx.x * 256 + threadIdx.x;
    if (g < n) { deg[g] = 1; return; }
    g -= n;
    if (g < 32 * 256) {
        int kk = g & 7, c = (g >> 3) & 255, kb = g >> 11;
        int k = kb * 8 + kk;
        float v = (c < 128) ? Wl1[k * 128 + c] : Wr1[k * 128 + (c - 128)];
        Wb1[g] = f2bf(v);
        return;
    }
    g -= 32 * 256;
    if (g < 128 * 256) {
        int kk = g & 7, c = (g >> 3) & 255, kb = g >> 11;
        int k = kb * 8 + kk;
        float v = (c < 128) ? Wl2[k * 128 + c] : Wr2[k * 128 + (c - 128)];
        Wb2[g] = f2bf(v);
    }
}

// ---------------- CSR build ----------------
// deg starts at 1: self-loop of node i owns rank 0 (scattered in fused scan23).

__global__ void k_count_rank(const int* __restrict__ ei, int E,
                             int* __restrict__ deg, int* __restrict__ epos) {
    int e = blockIdx.x * 256 + threadIdx.x;
    if (e >= E) return;
    int dst = ei[E + e];
    epos[e] = atomicAdd(&deg[dst], 1);
}

__global__ __launch_bounds__(1024) void k_scan1(const int* __restrict__ deg, int n,
                                                int* __restrict__ ex, int* __restrict__ bsum) {
    __shared__ int sw[16];
    int i = blockIdx.x * 1024 + threadIdx.x;
    int v = (i < n) ? deg[i] : 0;
    int lane = threadIdx.x & 63, w = threadIdx.x >> 6;
    int x = v;
    #pragma unroll
    for (int d = 1; d < 64; d <<= 1) {
        int t = __shfl_up(x, d);
        if (lane >= d) x += t;
    }
    if (lane == 63) sw[w] = x;
    __syncthreads();
    if (w == 0) {
        int t = (lane < 16) ? sw[lane] : 0;
        #pragma unroll
        for (int d = 1; d < 16; d <<= 1) {
            int u = __shfl_up(t, d);
            if (lane >= d) t += u;
        }
        if (lane < 16) sw[lane] = t;
    }
    __syncthreads();
    int woff = (w > 0) ? sw[w - 1] : 0;
    int incl = x + woff;
    if (i < n) ex[i] = incl - v;
    if (threadIdx.x == 1023) bsum[blockIdx.x] = incl;
}

// fused scan2+scan3: each block computes its bsum prefix in-block (nb <= 64),
// finalizes offsets, and scatters the self-loop at rank 0.
__global__ __launch_bounds__(1024) void k_scan23(int* __restrict__ ex, const int* __restrict__ bsum,
                                                 int n, int nb, int* __restrict__ csr_src) {
    __shared__ int sprefix;
    if (threadIdx.x < 64) {
        int lane = threadIdx.x;
        int t = (lane < (int)blockIdx.x) ? bsum[lane] : 0;
        #pragma unroll
        for (int d = 1; d < 64; d <<= 1) t += __shfl_xor(t, d);
        if (lane == 0) sprefix = t;
    }
    __syncthreads();
    int i = blockIdx.x * 1024 + threadIdx.x;
    if (i < n) {
        int off = ex[i] + sprefix;
        ex[i] = off;
        csr_src[off] = i;
    }
}

__global__ void k_scatter(const int* __restrict__ ei, const int* __restrict__ epos,
                          const int* __restrict__ offsets, int E,
                          int* __restrict__ csr_src) {
    int e = blockIdx.x * 256 + threadIdx.x;
    if (e >= E) return;
    int src = ei[e], dst = ei[E + e];
    csr_src[offsets[dst] + epos[e]] = src;
}

// ---------------- dual linear via MFMA: [outL|outR] = X @ [Wl|Wr], bf16 out ----------------
// 64 nodes x 256 cols per block, 4 waves; wave w owns cols [64w, 64w+64).
template <int K>
__global__ __launch_bounds__(256) void dual_linear_mfma(const float* __restrict__ X,
                                                        const unsigned short* __restrict__ Wb,
                                                        unsigned short* __restrict__ outL,
                                                        unsigned short* __restrict__ outR, int n) {
    constexpr int INS = K + 8;
    __shared__ unsigned short buf[64 * 264];
    int tid = threadIdx.x;
    int lane = tid & 63;
    int w = tid >> 6;
    int n0 = blockIdx.x * 64;

    constexpr int F4R = K / 4;
    constexpr int ITS = 64 * F4R / 256;
    #pragma unroll
    for (int it = 0; it < ITS; ++it) {
        int f = it * 256 + tid;
        int row = f / F4R, c4 = f % F4R;
        int gn = n0 + row;
        float4 v = make_float4(0.f, 0.f, 0.f, 0.f);
        if (gn < n) v = *(const float4*)&X[(size_t)gn * K + c4 * 4];
        ushort4 o;
        o.x = f2bf(v.x); o.y = f2bf(v.y); o.z = f2bf(v.z); o.w = f2bf(v.w);
        *(ushort4*)&buf[row * INS + c4 * 4] = o;
    }
    __syncthreads();

    int l15 = lane & 15, l4 = lane >> 4;
    int c0 = w * 64;

    f32x4 acc[4][4];
    #pragma unroll
    for (int rt = 0; rt < 4; ++rt)
        #pragma unroll
        for (int ct = 0; ct < 4; ++ct)
            acc[rt][ct] = (f32x4)(0.f);

    #pragma unroll
    for (int ks = 0; ks < K / 32; ++ks) {
        bf16x8 a[4], b[4];
        #pragma unroll
        for (int rt = 0; rt < 4; ++rt)
            a[rt] = *(const bf16x8*)&buf[(rt * 16 + l15) * INS + ks * 32 + l4 * 8];
        #pragma unroll
        for (int ct = 0; ct < 4; ++ct)
            b[ct] = *(const bf16x8*)&Wb[(((ks * 4 + l4) * 256) + (c0 + ct * 16 + l15)) * 8];
        #pragma unroll
        for (int rt = 0; rt < 4; ++rt)
            #pragma unroll
            for (int ct = 0; ct < 4; ++ct)
                acc[rt][ct] = __builtin_amdgcn_mfma_f32_16x16x32_bf16(a[rt], b[ct], acc[rt][ct], 0, 0, 0);
    }
    __syncthreads();

    #pragma unroll
    for (int rt = 0; rt < 4; ++rt)
        #pragma unroll
        for (int ct = 0; ct < 4; ++ct)
            #pragma unroll
            for (int j = 0; j < 4; ++j)
                buf[(rt * 16 + l4 * 4 + j) * 264 + c0 + ct * 16 + l15] = f2bf(acc[rt][ct][j]);
    __syncthreads();

    #pragma unroll
    for (int it = 0; it < 8; ++it) {
        int f = it * 256 + tid;
        int row = f >> 5, cw = f & 31;
        int gn = n0 + row;
        if (gn < n) {
            uint4 v = *(const uint4*)&buf[row * 264 + cw * 8];
            if (cw < 16) *(uint4*)&outL[(size_t)gn * 128 + cw * 8] = v;
            else         *(uint4*)&outR[(size_t)gn * 128 + (cw - 16) * 8] = v;
        }
    }
}

// ---------------- GATv2 aggregation with fused LN(+residual)+ELU epilogue ----------------
// one wave per dst node; lane lc=lane&15 owns 8 channels (head=lc>>2), eg=lane>>4
// = edge slot. Edge indices loaded DIRECTLY per 16-lane group (sp[i], one cache
// line per wave-step) -- no preload batch, no ds_bpermute broadcasts, no batch
// bookkeeping. 2-deep gather prefetch (round-8 proven depth).

struct GatAcc {
    float den;
    float nb[8];
};

template <bool CHECKED>
__device__ __forceinline__ void gat_edge(uint4 r, bool valid,
                                         const float4& xrA, const float4& xrB,
                                         const float4& atA, const float4& atB,
                                         GatAcc& g) {
    float e0 = bflo(r.x), e1 = bfhi(r.x);
    float e2 = bflo(r.y), e3 = bfhi(r.y);
    float e4 = bflo(r.z), e5 = bfhi(r.z);
    float e6 = bflo(r.w), e7 = bfhi(r.w);
    float v0 = e0 + xrA.x; v0 = fmaxf(v0, SLOPE * v0);
    float v1 = e1 + xrA.y; v1 = fmaxf(v1, SLOPE * v1);
    float v2 = e2 + xrA.z; v2 = fmaxf(v2, SLOPE * v2);
    float v3 = e3 + xrA.w; v3 = fmaxf(v3, SLOPE * v3);
    float v4 = e4 + xrB.x; v4 = fmaxf(v4, SLOPE * v4);
    float v5 = e5 + xrB.y; v5 = fmaxf(v5, SLOPE * v5);
    float v6 = e6 + xrB.z; v6 = fmaxf(v6, SLOPE * v6);
    float v7 = e7 + xrB.w; v7 = fmaxf(v7, SLOPE * v7);
    float t = v0 * atA.x;
    t = fmaf(v1, atA.y, t);
    t = fmaf(v2, atA.z, t);
    t = fmaf(v3, atA.w, t);
    t = fmaf(v4, atB.x, t);
    t = fmaf(v5, atB.y, t);
    t = fmaf(v6, atB.z, t);
    t = fmaf(v7, atB.w, t);
    t += __shfl_xor(t, 1);
    t += __shfl_xor(t, 2);
    float a = __expf(t);
    if (CHECKED) a = valid ? a : 0.f;
    g.den += a;
    g.nb[0] = fmaf(a, e0, g.nb[0]);
    g.nb[1] = fmaf(a, e1, g.nb[1]);
    g.nb[2] = fmaf(a, e2, g.nb[2]);
    g.nb[3] = fmaf(a, e3, g.nb[3]);
    g.nb[4] = fmaf(a, e4, g.nb[4]);
    g.nb[5] = fmaf(a, e5, g.nb[5]);
    g.nb[6] = fmaf(a, e6, g.nb[6]);
    g.nb[7] = fmaf(a, e7, g.nb[7]);
}

__global__ __launch_bounds__(256) void gat_aggr(const unsigned short* __restrict__ xl,
                                                const unsigned short* __restrict__ xr,
                                                const int* __restrict__ csr_src,
                                                const int* __restrict__ offsets,
                                                const int* __restrict__ deg,
                                                const float* __restrict__ att,
                                                const float* __restrict__ bias,
                                                const float* __restrict__ gamma,
                                                const float* __restrict__ beta,
                                                const float* __restrict__ hprev,
                                                float* __restrict__ hout,
                                                int n, int layer) {
    int wave = threadIdx.x >> 6;
    int lane = threadIdx.x & 63;
    int dst = blockIdx.x * 4 + wave;
    if (dst >= n) return;

    int lc = lane & 15;
    int eg = lane >> 4;
    int c0 = lc * 8;
    unsigned cb = (unsigned)(lc * 16);

    float4 atA = *(const float4*)&att[c0];
    float4 atB = *(const float4*)&att[c0 + 4];
    const char* xlb = (const char*)xl;

    uint4 xrr = *(const uint4*)((const char*)xr + (unsigned)dst * 256u + cb);
    float4 xrA = make_float4(bflo(xrr.x), bfhi(xrr.x), bflo(xrr.y), bfhi(xrr.y));
    float4 xrB = make_float4(bflo(xrr.z), bfhi(xrr.z), bflo(xrr.w), bfhi(xrr.w));

    int start = offsets[dst];
    int cnt = deg[dst];
    const int* sp = csr_src + start;

    GatAcc g;
    g.den = 0.f;
    #pragma unroll
    for (int j = 0; j < 8; ++j) g.nb[j] = 0.f;

    int nq = cnt >> 2;           // full quads
    int tail = cnt & 3;
    int i = eg;
    int end2 = eg + ((nq & ~1) << 2);
    for (; i < end2; i += 8) {
        int s0 = sp[i];
        int s1 = sp[i + 4];
        uint4 r0 = *(const uint4*)(xlb + (((unsigned)s0 << 8) + cb));
        uint4 r1 = *(const uint4*)(xlb + (((unsigned)s1 << 8) + cb));
        gat_edge<false>(r0, true, xrA, xrB, atA, atB, g);
        gat_edge<false>(r1, true, xrA, xrB, atA, atB, g);
    }
    if (nq & 1) {
        int s0 = sp[i];
        uint4 r0 = *(const uint4*)(xlb + (((unsigned)s0 << 8) + cb));
        gat_edge<false>(r0, true, xrA, xrB, atA, atB, g);
        i += 4;
    }
    if (tail) {
        int idx = (i < cnt) ? i : (cnt - 1);   // clamp invalid eg slots
        int s0 = sp[idx];
        uint4 r0 = *(const uint4*)(xlb + (((unsigned)s0 << 8) + cb));
        gat_edge<true>(r0, eg < tail, xrA, xrB, atA, atB, g);
    }

    g.den += __shfl_xor(g.den, 16);
    g.den += __shfl_xor(g.den, 32);
    #pragma unroll
    for (int j = 0; j < 8; ++j) {
        g.nb[j] += __shfl_xor(g.nb[j], 16);
        g.nb[j] += __shfl_xor(g.nb[j], 32);
    }

    float inv = 1.f / g.den;
    float4 bA = *(const float4*)&bias[c0];
    float4 bB = *(const float4*)&bias[c0 + 4];
    float v[8];
    v[0] = fmaf(g.nb[0], inv, bA.x);
    v[1] = fmaf(g.nb[1], inv, bA.y);
    v[2] = fmaf(g.nb[2], inv, bA.z);
    v[3] = fmaf(g.nb[3], inv, bA.w);
    v[4] = fmaf(g.nb[4], inv, bB.x);
    v[5] = fmaf(g.nb[5], inv, bB.y);
    v[6] = fmaf(g.nb[6], inv, bB.z);
    v[7] = fmaf(g.nb[7], inv, bB.w);

    float s1 = 0.f, s2 = 0.f;
    #pragma unroll
    for (int j = 0; j < 8; ++j) {
        s1 += v[j];
        s2 = fmaf(v[j], v[j], s2);
    }
    #pragma unroll
    for (int d = 1; d < 16; d <<= 1) {
        s1 += __shfl_xor(s1, d);
        s2 += __shfl_xor(s2, d);
    }
    float mu = s1 * (1.f / 128.f);
    float var = s2 * (1.f / 128.f) - mu * mu;
    float rs = rsqrtf(var + LNEPS);

    float4 gA = *(const float4*)&gamma[c0];
    float4 gB = *(const float4*)&gamma[c0 + 4];
    float4 beA = *(const float4*)&beta[c0];
    float4 beB = *(const float4*)&beta[c0 + 4];
    float y[8];
    y[0] = (v[0] - mu) * rs * gA.x + beA.x;
    y[1] = (v[1] - mu) * rs * gA.y + beA.y;
    y[2] = (v[2] - mu) * rs * gA.z + beA.z;
    y[3] = (v[3] - mu) * rs * gA.w + beA.w;
    y[4] = (v[4] - mu) * rs * gB.x + beB.x;
    y[5] = (v[5] - mu) * rs * gB.y + beB.y;
    y[6] = (v[6] - mu) * rs * gB.z + beB.z;
    y[7] = (v[7] - mu) * rs * gB.w + beB.w;

    if (layer == 2) {
        const float* hp = &hprev[(size_t)dst * HID + c0];
        float4 hA = *(const float4*)hp;
        float4 hB = *(const float4*)(hp + 4);
        y[0] += hA.x; y[1] += hA.y; y[2] += hA.z; y[3] += hA.w;
        y[4] += hB.x; y[5] += hB.y; y[6] += hB.z; y[7] += hB.w;
    }
    #pragma unroll
    for (int j = 0; j < 8; ++j)
        y[j] = (y[j] > 0.f) ? y[j] : (__expf(y[j]) - 1.f);

    if (eg == 0) {
        float* op = &hout[(size_t)dst * HID + c0];
        *(float4*)op = make_float4(y[0], y[1], y[2], y[3]);
        *(float4*)(op + 4) = make_float4(y[4], y[5], y[6], y[7]);
    }
}

// ---------------- fused prediction + uncertainty heads (register-blocked GEMM) ----------------
__global__ __launch_bounds__(256) void k_heads(const float* __restrict__ hf,
                                               const float* __restrict__ Wp1, const float* __restrict__ bp1,
                                               const float* __restrict__ Wp2, const float* __restrict__ bp2,
                                               const float* __restrict__ Wu1, const float* __restrict__ bu1,
                                               const float* __restrict__ Wu2, const float* __restrict__ bu2,
                                               float* __restrict__ out, int n) {
    __shared__ float sXH[64 * 132];
    __shared__ float sW[32 * 96];
    __shared__ float sW2[64 * 6 + 32 * 6];
    int tid = threadIdx.x;
    int node0 = blockIdx.x * 64;

    for (int i = tid; i < 576; i += 256) sW2[i] = (i < 384) ? Wp2[i] : Wu2[i - 384];

    {
        int row = tid >> 2, seg = tid & 3;
        int gn = node0 + row;
        const float* src = &hf[(size_t)gn * HID + seg * 32];
        float* dst = &sXH[row * 132 + seg * 32];
        #pragma unroll
        for (int q = 0; q < 8; ++q) {
            float4 v = make_float4(0.f, 0.f, 0.f, 0.f);
            if (gn < n) v = *(const float4*)&src[q * 4];
            *(float4*)&dst[q * 4] = v;
        }
    }

    int cg = tid & 15;
    int ng = tid >> 4;
    int c0 = cg * 6;

    float acc[4][6];
    #pragma unroll
    for (int i = 0; i < 4; ++i)
        #pragma unroll
        for (int j = 0; j < 6; ++j) acc[i][j] = 0.f;

    for (int kc = 0; kc < HID; kc += 32) {
        __syncthreads();
        #pragma unroll
        for (int q = 0; q < 3; ++q) {
            int g = q * 256 + tid;
            int r = g / 24, c4 = g % 24;
            int c = c4 * 4;
            const float* src = (c < 64) ? &Wp1[(size_t)(kc + r) * 64 + c]
                                        : &Wu1[(size_t)(kc + r) * 32 + (c - 64)];
            *(float4*)&sW[r * 96 + c] = *(const float4*)src;
        }
        __syncthreads();
        #pragma unroll
        for (int k = 0; k < 32; ++k) {
            const float* wr = &sW[k * 96 + c0];
            float w0 = wr[0], w1 = wr[1], w2 = wr[2], w3 = wr[3], w4 = wr[4], w5 = wr[5];
            #pragma unroll
            for (int i = 0; i < 4; ++i) {
                float xv = sXH[(ng * 4 + i) * 132 + kc + k];
                acc[i][0] = fmaf(xv, w0, acc[i][0]);
                acc[i][1] = fmaf(xv, w1, acc[i][1]);
                acc[i][2] = fmaf(xv, w2, acc[i][2]);
                acc[i][3] = fmaf(xv, w3, acc[i][3]);
                acc[i][4] = fmaf(xv, w4, acc[i][4]);
                acc[i][5] = fmaf(xv, w5, acc[i][5]);
            }
        }
    }

    __syncthreads();
    float bv[6];
    #pragma unroll
    for (int j = 0; j < 6; ++j) {
        int c = c0 + j;
        bv[j] = (c < 64) ? bp1[c] : bu1[c - 64];
    }
    #pragma unroll
    for (int i = 0; i < 4; ++i) {
        int row = ng * 4 + i;
        #pragma unroll
        for (int j = 0; j < 6; ++j) {
            float v = acc[i][j] + bv[j];
            sXH[row * 97 + c0 + j] = fmaxf(v, 0.f);
        }
    }
    __syncthreads();

    int nl = tid & 63;
    int g = tid >> 6;
    int node = node0 + nl;
    float a0 = 0.f, a1 = 0.f, a2 = 0.f;
    if (g < 2) {
        int j0 = 3 * g;
        const float* hrow = &sXH[nl * 97];
        #pragma unroll 8
        for (int k = 0; k < 64; ++k) {
            float hv = hrow[k];
            a0 = fmaf(hv, sW2[k * 6 + j0], a0);
            a1 = fmaf(hv, sW2[k * 6 + j0 + 1], a1);
            a2 = fmaf(hv, sW2[k * 6 + j0 + 2], a2);
        }
        if (node < n) {
            size_t pb = (size_t)node * 6 + j0;
            out[pb]     = a0 + bp2[j0];
            out[pb + 1] = a1 + bp2[j0 + 1];
            out[pb + 2] = a2 + bp2[j0 + 2];
        }
    } else {
        int j0 = 3 * (g - 2);
        const float* hrow = &sXH[nl * 97 + 64];
        #pragma unroll 8
        for (int k = 0; k < 32; ++k) {
            float hv = hrow[k];
            a0 = fmaf(hv, sW2[384 + k * 6 + j0], a0);
            a1 = fmaf(hv, sW2[384 + k * 6 + j0 + 1], a1);
            a2 = fmaf(hv, sW2[384 + k * 6 + j0 + 2], a2);
        }
        if (node < n) {
            float z0 = a0 + bu2[j0], z1 = a1 + bu2[j0 + 1], z2 = a2 + bu2[j0 + 2];
            size_t ub = (size_t)n * 6 + (size_t)node * 6 + j0;
            out[ub]     = fmaxf(z0, 0.f) + log1pf(__expf(-fabsf(z0)));
            out[ub + 1] = fmaxf(z1, 0.f) + log1pf(__expf(-fabsf(z1)));
            out[ub + 2] = fmaxf(z2, 0.f) + log1pf(__expf(-fabsf(z2)));
        }
    }
}

// ---------------- launch ----------------

extern "C" void kernel_launch(void* const* d_in, const int* in_sizes, int n_in,
                              void* d_out, int out_size, void* d_ws, size_t ws_size,
                              hipStream_t stream) {
    const float* x   = (const float*)d_in[0];
    const int*   ei  = (const int*)d_in[1];
    const float* Wl1 = (const float*)d_in[2];
    const float* Wr1 = (const float*)d_in[3];
    const float* att1 = (const float*)d_in[4];
    const float* bias1 = (const float*)d_in[5];
    const float* g1 = (const float*)d_in[6];
    const float* b1 = (const float*)d_in[7];
    const float* Wl2 = (const float*)d_in[8];
    const float* Wr2 = (const float*)d_in[9];
    const float* att2 = (const float*)d_in[10];
    const float* bias2 = (const float*)d_in[11];
    const float* g2 = (const float*)d_in[12];
    const float* b2 = (const float*)d_in[13];
    const float* Wp1 = (const float*)d_in[14];
    const float* bp1 = (const float*)d_in[15];
    const float* Wp2 = (const float*)d_in[16];
    const float* bp2 = (const float*)d_in[17];
    const float* Wu1 = (const float*)d_in[18];
    const float* bu1 = (const float*)d_in[19];
    const float* Wu2 = (const float*)d_in[20];
    const float* bu2 = (const float*)d_in[21];

    int N_ = in_sizes[0] / 32;
    int E_ = in_sizes[1] / 2;
    int EA = E_ + N_;

    // workspace layout
    char* p = (char*)d_ws;
    size_t fbytes = (size_t)N_ * HID * sizeof(float);
    unsigned short* xl = (unsigned short*)p; p += fbytes / 2;  // bf16
    unsigned short* xr = (unsigned short*)p; p += fbytes / 2;  // bf16
    float* h  = (float*)p; p += fbytes;
    float* hf = (float*)p; p += fbytes;
    auto align16 = [](size_t s) { return (s + 15) & ~(size_t)15; };
    int* deg     = (int*)p; p += align16((size_t)N_ * 4);
    int* offsets = (int*)p; p += align16((size_t)N_ * 4);
    int* bsum    = (int*)p; p += 64 * 4;
    int* csr_src = (int*)p; p += align16((size_t)EA * 4);
    unsigned short* Wb1 = (unsigned short*)p; p += 32 * 256 * 2;
    unsigned short* Wb2 = (unsigned short*)p; p += 128 * 256 * 2;
    // epos aliases hf: dead before gat layer-2 writes hf
    int* epos = (int*)hf;

    int nScan = cdiv(N_, 1024);
    int setupN = N_ + 32 * 256 + 128 * 256;
    k_setup<<<cdiv(setupN, 256), 256, 0, stream>>>(deg, N_, Wl1, Wr1, Wb1, Wl2, Wr2, Wb2);
    k_count_rank<<<cdiv(E_, 256), 256, 0, stream>>>(ei, E_, deg, epos);
    k_scan1<<<nScan, 1024, 0, stream>>>(deg, N_, offsets, bsum);
    k_scan23<<<nScan, 1024, 0, stream>>>(offsets, bsum, N_, nScan, csr_src);
    k_scatter<<<cdiv(E_, 256), 256, 0, stream>>>(ei, epos, offsets, E_, csr_src);

    // layer 1
    dual_linear_mfma<32><<<cdiv(N_, 64), 256, 0, stream>>>(x, Wb1, xl, xr, N_);
    gat_aggr<<<cdiv(N_, 4), 256, 0, stream>>>(xl, xr, csr_src, offsets, deg,
                                              att1, bias1, g1, b1, nullptr, h, N_, 1);
    // layer 2
    dual_linear_mfma<128><<<cdiv(N_, 64), 256, 0, stream>>>(h, Wb2, xl, xr, N_);
    gat_aggr<<<cdiv(N_, 4), 256, 0, stream>>>(xl, xr, csr_src, offsets, deg,
                                              att2, bias2, g2, b2, h, hf, N_, 2);
    // heads
    k_heads<<<cdiv(N_, 64), 256, 0, stream>>>(hf, Wp1, bp1, Wp2, bp2,
                                              Wu1, bu1, Wu2, bu2, (float*)d_out, N_);
}